// Round 7
// baseline (626.771 us; speedup 1.0000x reference)
//
#include <hip/hip_runtime.h>
#include <stdint.h>
#include <stddef.h>

#define NB 4
#define NC 256
#define NSP 4096
#define NG 32
#define CPG 8
#define GEPS 1e-5f
#define SCALE 0.0625f  // d^-0.5, d=256
#define NROWS (NB * NSP)  // 16384 global q-rows

typedef __attribute__((ext_vector_type(8))) short s8v;
typedef __attribute__((ext_vector_type(4))) float f4v;
typedef __attribute__((ext_vector_type(4))) unsigned short us4v;

__device__ __forceinline__ float b2f(unsigned short h) {
  union { unsigned u; float f; } x; x.u = ((unsigned)h) << 16; return x.f;
}
__device__ __forceinline__ unsigned short f2b(float f) {
  union { float f; unsigned u; } x; x.f = f;
  unsigned r = x.u + 0x7fffu + ((x.u >> 16) & 1u);
  return (unsigned short)(r >> 16);
}

// -------------------- fp32 -> bf16 convert (weights) --------------------
__global__ __launch_bounds__(256) void cvt_kernel(const float* __restrict__ in,
                                                  unsigned short* __restrict__ out, int n) {
  int i = (blockIdx.x * 256 + threadIdx.x) * 4;
  if (i < n) {
    float4 v = *(const float4*)(in + i);
    us4v p;
    p[0] = f2b(v.x); p[1] = f2b(v.y); p[2] = f2b(v.z); p[3] = f2b(v.w);
    *(us4v*)(out + i) = p;
  }
}

// -------------------- GroupNorm: x fp32 (B,C,N) -> xn bf16 (B,N,C) --------------------
__global__ __launch_bounds__(256) void gn_kernel(
    const float* __restrict__ x, const float* __restrict__ w,
    const float* __restrict__ bias, unsigned short* __restrict__ xn) {
  int b = blockIdx.x >> 5;
  int g = blockIdx.x & 31;
  const float* xp = x + ((size_t)b * NC + (size_t)g * CPG) * NSP;
  int t = threadIdx.x;
  float s = 0.f, ss = 0.f;
  for (int i = 4 * t; i < CPG * NSP; i += 1024) {
    float4 v = *(const float4*)(xp + i);
    s += v.x + v.y + v.z + v.w;
    ss += v.x * v.x + v.y * v.y + v.z * v.z + v.w * v.w;
  }
  __shared__ float r1[256], r2[256];
  r1[t] = s; r2[t] = ss;
  __syncthreads();
  for (int off = 128; off > 0; off >>= 1) {
    if (t < off) { r1[t] += r1[t + off]; r2[t] += r2[t + off]; }
    __syncthreads();
  }
  float mean = r1[0] * (1.f / (CPG * NSP));
  float var  = r2[0] * (1.f / (CPG * NSP)) - mean * mean;
  float rstd = rsqrtf(var + GEPS);
  float wv[CPG], bv[CPG];
  for (int c = 0; c < CPG; c++) {
    wv[c] = w[g * CPG + c] * rstd;
    bv[c] = bias[g * CPG + c] - mean * wv[c];
  }
  for (int n = t; n < NSP; n += 256) {
    s8v pk;
    for (int c = 0; c < CPG; c++) {
      float v = xp[(size_t)c * NSP + n];
      ((unsigned short*)&pk)[c] = f2b(v * wv[c] + bv[c]);
    }
    *(s8v*)(xn + ((size_t)(b * NSP + n) * NC + g * CPG)) = pk;
  }
}

// ------ Generic NT GEMM: C[m][n] = scale*sum_k A[m][k]*Bt[n][k] (+bias[m]) (+res) ------
template<int STORE_T, int HAS_BIAS, int HAS_RES, int F32OUT>
__global__ __launch_bounds__(256) void gemm_nt(
    const unsigned short* __restrict__ A, const unsigned short* __restrict__ Bt,
    void* __restrict__ Cv, const float* __restrict__ bias,
    const float* __restrict__ res,
    int M, int N, int K, int ldC, float scale,
    long long sA, long long sB, long long sC, long long sR) {
  A  += (size_t)blockIdx.z * sA;
  Bt += (size_t)blockIdx.z * sB;
  if (HAS_RES) res += (size_t)blockIdx.z * sR;
  const int m0 = blockIdx.y * 128, n0 = blockIdx.x * 128;
  __shared__ unsigned short As[128 * 32], Bs[128 * 32];
  const int t = threadIdx.x;
  const int lane = t & 63, wave = t >> 6;
  const int wm = (wave >> 1) * 64, wn = (wave & 1) * 64;
  const int l16 = lane & 15, quad = lane >> 4;
  const int srow = t >> 2, skc = (t & 3) * 8;

  f4v acc[4][4];
  for (int mi = 0; mi < 4; mi++)
    for (int ni = 0; ni < 4; ni++)
      acc[mi][ni] = (f4v){0.f, 0.f, 0.f, 0.f};

  const unsigned short* Ag0 = A  + (size_t)(m0 + srow) * K + skc;
  const unsigned short* Ag1 = A  + (size_t)(m0 + srow + 64) * K + skc;
  const unsigned short* Bg0 = Bt + (size_t)(n0 + srow) * K + skc;
  const unsigned short* Bg1 = Bt + (size_t)(n0 + srow + 64) * K + skc;

  for (int k0 = 0; k0 < K; k0 += 32) {
    s8v a0 = *(const s8v*)(Ag0 + k0);
    s8v a1 = *(const s8v*)(Ag1 + k0);
    s8v b0 = *(const s8v*)(Bg0 + k0);
    s8v b1 = *(const s8v*)(Bg1 + k0);
    __syncthreads();
    *(s8v*)(As + srow * 32 + skc) = a0;
    *(s8v*)(As + (srow + 64) * 32 + skc) = a1;
    *(s8v*)(Bs + srow * 32 + skc) = b0;
    *(s8v*)(Bs + (srow + 64) * 32 + skc) = b1;
    __syncthreads();
    s8v af[4], bfr[4];
    for (int mi = 0; mi < 4; mi++)
      af[mi] = *(const s8v*)(As + (wm + mi * 16 + l16) * 32 + quad * 8);
    for (int ni = 0; ni < 4; ni++)
      bfr[ni] = *(const s8v*)(Bs + (wn + ni * 16 + l16) * 32 + quad * 8);
    for (int mi = 0; mi < 4; mi++)
      for (int ni = 0; ni < 4; ni++)
        acc[mi][ni] = __builtin_amdgcn_mfma_f32_16x16x32_bf16(af[mi], bfr[ni], acc[mi][ni], 0, 0, 0);
  }

  for (int mi = 0; mi < 4; mi++) {
    const int rb = m0 + wm + mi * 16 + quad * 4;
    for (int ni = 0; ni < 4; ni++) {
      const int col = n0 + wn + ni * 16 + l16;
      f4v a = acc[mi][ni];
      if (F32OUT) {
        float* C = (float*)Cv + (size_t)blockIdx.z * sC;
        for (int r = 0; r < 4; r++) {
          float v = a[r] * scale;
          if (HAS_BIAS) v += bias[rb + r];
          if (HAS_RES) v += res[(size_t)(rb + r) * ldC + col];
          C[(size_t)(rb + r) * ldC + col] = v;
        }
      } else {
        unsigned short* C = (unsigned short*)Cv + (size_t)blockIdx.z * sC;
        if (STORE_T) {
          us4v pk;
          for (int r = 0; r < 4; r++) {
            float v = a[r] * scale;
            if (HAS_BIAS) v += bias[rb + r];
            pk[r] = (unsigned short)f2b(v);
          }
          *(us4v*)(C + (size_t)col * ldC + rb) = pk;
        } else {
          for (int r = 0; r < 4; r++) {
            float v = a[r] * scale;
            if (HAS_BIAS) v += bias[rb + r];
            if (HAS_RES) v += res[(size_t)(rb + r) * ldC + col];
            C[(size_t)(rb + r) * ldC + col] = f2b(v);
          }
        }
      }
    }
  }
}

// ---- Flash v2: barrier-free, direct-global K/V frags, j-split x2 ----
// grid (NSP/64, NB, 2), 256 thr. Wave w owns Q-rows qt*64+w*16..+16, j in [js*2048,+2048).
// Writes unnormalized partial O (fp32) + (m,l) per row.
__global__ __launch_bounds__(256) void flash2_kernel(
    const unsigned short* __restrict__ q, const unsigned short* __restrict__ k,
    const unsigned short* __restrict__ v, float* __restrict__ Opart,
    float2* __restrict__ MLpart) {
  const int qt = blockIdx.x, b = blockIdx.y, js = blockIdx.z;
  const size_t sNC = (size_t)NSP * NC;
  const unsigned short* qb = q + b * sNC;
  const unsigned short* kb = k + b * sNC;
  const unsigned short* vb = v + b * sNC;
  const int t = threadIdx.x, lane = t & 63, w = t >> 6;
  const int l16 = lane & 15, quad = lane >> 4;

  __shared__ unsigned short Ps[4][16 * 40];  // per-wave P transpose scratch
  unsigned short* Pw = Ps[w];

  const int ibase = qt * 64 + w * 16;
  s8v qf[8];
  for (int kc = 0; kc < 8; kc++)
    qf[kc] = *(const s8v*)(qb + (size_t)(ibase + l16) * NC + kc * 32 + quad * 8);

  f4v accO[16];
  for (int dt = 0; dt < 16; dt++) accO[dt] = (f4v){0.f, 0.f, 0.f, 0.f};
  float m_r[4], l_r[4];
  for (int r = 0; r < 4; r++) { m_r[r] = -1e30f; l_r[r] = 0.f; }

  const int jbeg = js * (NSP / 2);
  for (int jt = 0; jt < 32; jt++) {
    const int j0 = jbeg + jt * 64;
    // ---- QK^T over 4 j-subtiles of 16 (K frags direct from global, L2-hot) ----
    f4v accS[4];
    for (int s = 0; s < 4; s++) accS[s] = (f4v){0.f, 0.f, 0.f, 0.f};
    for (int kc = 0; kc < 8; kc++) {
      for (int s = 0; s < 4; s++) {
        s8v kf = *(const s8v*)(kb + (size_t)(j0 + s * 16 + l16) * NC + kc * 32 + quad * 8);
        accS[s] = __builtin_amdgcn_mfma_f32_16x16x32_bf16(qf[kc], kf, accS[s], 0, 0, 0);
      }
    }
    // ---- online softmax per row r; j runs over (subtile s, lane l16) ----
    float al_r[4], p[4][4];
    for (int r = 0; r < 4; r++) {
      float mv = fmaxf(fmaxf(accS[0][r], accS[1][r]), fmaxf(accS[2][r], accS[3][r])) * SCALE;
      for (int msk = 1; msk < 16; msk <<= 1) mv = fmaxf(mv, __shfl_xor(mv, msk, 64));
      const float mt = fmaxf(m_r[r], mv);
      const float al = __expf(m_r[r] - mt);
      float s_sum = 0.f;
      for (int s = 0; s < 4; s++) {
        const float pv = __expf(accS[s][r] * SCALE - mt);
        p[s][r] = pv; s_sum += pv;
      }
      for (int msk = 1; msk < 16; msk <<= 1) s_sum += __shfl_xor(s_sum, msk, 64);
      l_r[r] = l_r[r] * al + s_sum;
      m_r[r] = mt;
      al_r[r] = al;
    }
    for (int dt = 0; dt < 16; dt++)
      for (int r = 0; r < 4; r++) accO[dt][r] *= al_r[r];

    // ---- PV in 2 halves of 32 j: P C-layout -> LDS -> A-frag; V frags direct global ----
    for (int h = 0; h < 2; h++) {
      for (int n = 0; n < 2; n++)
        for (int r = 0; r < 4; r++)
          Pw[(quad * 4 + r) * 40 + n * 16 + l16] = f2b(p[2 * h + n][r]);
      s8v pf = *(const s8v*)(Pw + l16 * 40 + quad * 8);
      const int jh = j0 + h * 32;
      for (int dt = 0; dt < 16; dt++) {
        s8v vf = *(const s8v*)(vb + (size_t)(dt * 16 + l16) * NSP + jh + quad * 8);
        accO[dt] = __builtin_amdgcn_mfma_f32_16x16x32_bf16(pf, vf, accO[dt], 0, 0, 0);
      }
    }
  }

  // ---- store partials: O unnormalized fp32, (m,l) per row ----
  const int prow = b * NSP + ibase;  // global row base of this wave
  float* Op = Opart + ((size_t)js * NROWS + prow) * NC;
  for (int dt = 0; dt < 16; dt++)
    for (int r = 0; r < 4; r++)
      Op[(size_t)(quad * 4 + r) * NC + dt * 16 + l16] = accO[dt][r];
  if (l16 == 0)
    for (int r = 0; r < 4; r++)
      MLpart[(size_t)js * NROWS + prow + quad * 4 + r] = make_float2(m_r[r], l_r[r]);
}

// ---- merge 2 partials -> at (B,N,C) bf16. grid NROWS/4, 256 thr (wave per row). ----
__global__ __launch_bounds__(256) void merge_kernel(
    const float* __restrict__ Opart, const float2* __restrict__ MLpart,
    unsigned short* __restrict__ at) {
  const int t = threadIdx.x;
  const int row = blockIdx.x * 4 + (t >> 6);
  const int d0 = (t & 63) * 4;
  const float2 ml0 = MLpart[row];
  const float2 ml1 = MLpart[NROWS + row];
  const float m = fmaxf(ml0.x, ml1.x);
  const float e0 = __expf(ml0.x - m), e1 = __expf(ml1.x - m);
  const float inv = 1.f / (ml0.y * e0 + ml1.y * e1);
  const float4 o0 = *(const float4*)(Opart + (size_t)row * NC + d0);
  const float4 o1 = *(const float4*)(Opart + ((size_t)NROWS + row) * NC + d0);
  us4v pk;
  pk[0] = f2b((e0 * o0.x + e1 * o1.x) * inv);
  pk[1] = f2b((e0 * o0.y + e1 * o1.y) * inv);
  pk[2] = f2b((e0 * o0.z + e1 * o1.z) * inv);
  pk[3] = f2b((e0 * o0.w + e1 * o1.w) * inv);
  *(us4v*)(at + (size_t)row * NC + d0) = pk;
}

extern "C" void kernel_launch(void* const* d_in, const int* in_sizes, int n_in,
                              void* d_out, int out_size, void* d_ws, size_t ws_size,
                              hipStream_t stream) {
  const float* x      = (const float*)d_in[0];
  const float* norm_w = (const float*)d_in[1];
  const float* norm_b = (const float*)d_in[2];
  const float* qkv_w  = (const float*)d_in[3];
  const float* qkv_b  = (const float*)d_in[4];
  const float* proj_w = (const float*)d_in[5];
  const float* proj_b = (const float*)d_in[6];
  float* out = (float*)d_out;  // fp32 output

  char* ws = (char*)d_ws;
  unsigned short* wq = (unsigned short*)ws;                     // 384 KB
  unsigned short* wp = (unsigned short*)(ws + 3 * NC * NC * 2); // 128 KB
  char* wst = ws + (1 << 20);
  const size_t szBNC = (size_t)NB * NSP * NC * 2;  // 8.4 MB (bf16)
  unsigned short* xn = (unsigned short*)wst;              // reused as `at`
  unsigned short* q  = (unsigned short*)(wst + szBNC);
  unsigned short* k  = (unsigned short*)(wst + 2 * szBNC);
  unsigned short* v  = (unsigned short*)(wst + 3 * szBNC);
  unsigned short* at = xn;
  float*  Opart = (float*)(wst + 4 * szBNC);              // 2*16384*256 fp32 = 33.5 MB
  float2* MLpart = (float2*)(wst + 4 * szBNC + 2ull * NROWS * NC * 4);  // 256 KB
  // peak ws: 1 MB + 4*8.4 + 33.5 + 0.25 = 68.4 MB (proven-safe <= 76.6 MB)

  cvt_kernel<<<dim3(3 * NC * NC / 1024), 256, 0, stream>>>(qkv_w, wq, 3 * NC * NC);
  cvt_kernel<<<dim3(NC * NC / 1024), 256, 0, stream>>>(proj_w, wp, NC * NC);
  gn_kernel<<<dim3(NB * NG), 256, 0, stream>>>(x, norm_w, norm_b, xn);

  const long long sNC = (long long)NSP * NC;
  gemm_nt<1, 1, 0, 0><<<dim3(NSP / 128, NC / 128, NB), 256, 0, stream>>>(
      wq, xn, q, qkv_b, nullptr, NC, NSP, NC, NC, 1.f, 0, sNC, sNC, 0);
  gemm_nt<1, 1, 0, 0><<<dim3(NSP / 128, NC / 128, NB), 256, 0, stream>>>(
      wq + NC * NC, xn, k, qkv_b + NC, nullptr, NC, NSP, NC, NC, 1.f, 0, sNC, sNC, 0);
  gemm_nt<0, 1, 0, 0><<<dim3(NSP / 128, NC / 128, NB), 256, 0, stream>>>(
      wq + 2 * NC * NC, xn, v, qkv_b + 2 * NC, nullptr, NC, NSP, NC, NSP, 1.f, 0, sNC, sNC, 0);

  flash2_kernel<<<dim3(NSP / 64, NB, 2), 256, 0, stream>>>(q, k, v, Opart, MLpart);
  merge_kernel<<<dim3(NROWS / 4), 256, 0, stream>>>(Opart, MLpart, at);

  gemm_nt<0, 1, 1, 1><<<dim3(NSP / 128, NC / 128, NB), 256, 0, stream>>>(
      wp, at, out, proj_b, x, NC, NSP, NC, NSP, 1.f, 0, sNC, sNC, sNC);
}

// Round 8
// 399.855 us; speedup vs baseline: 1.5675x; 1.5675x over previous
//
#include <hip/hip_runtime.h>
#include <stdint.h>
#include <stddef.h>

#define NB 4
#define NC 256
#define NSP 4096
#define NG 32
#define CPG 8
#define GEPS 1e-5f
#define SCALE 0.0625f  // d^-0.5, d=256
#define NROWS (NB * NSP)  // 16384 global q-rows
#define JSPLIT 4

typedef __attribute__((ext_vector_type(8))) short s8v;
typedef __attribute__((ext_vector_type(4))) float f4v;
typedef __attribute__((ext_vector_type(4))) unsigned short us4v;

__device__ __forceinline__ float b2f(unsigned short h) {
  union { unsigned u; float f; } x; x.u = ((unsigned)h) << 16; return x.f;
}
__device__ __forceinline__ unsigned short f2b(float f) {
  union { float f; unsigned u; } x; x.f = f;
  unsigned r = x.u + 0x7fffu + ((x.u >> 16) & 1u);
  return (unsigned short)(r >> 16);
}

// -------------------- fp32 -> bf16 convert (weights) --------------------
__global__ __launch_bounds__(256) void cvt_kernel(const float* __restrict__ in,
                                                  unsigned short* __restrict__ out, int n) {
  int i = (blockIdx.x * 256 + threadIdx.x) * 4;
  if (i < n) {
    float4 v = *(const float4*)(in + i);
    us4v p;
    p[0] = f2b(v.x); p[1] = f2b(v.y); p[2] = f2b(v.z); p[3] = f2b(v.w);
    *(us4v*)(out + i) = p;
  }
}

// -------------------- GroupNorm: x fp32 (B,C,N) -> xn bf16 (B,N,C) --------------------
__global__ __launch_bounds__(256) void gn_kernel(
    const float* __restrict__ x, const float* __restrict__ w,
    const float* __restrict__ bias, unsigned short* __restrict__ xn) {
  int b = blockIdx.x >> 5;
  int g = blockIdx.x & 31;
  const float* xp = x + ((size_t)b * NC + (size_t)g * CPG) * NSP;
  int t = threadIdx.x;
  float s = 0.f, ss = 0.f;
  for (int i = 4 * t; i < CPG * NSP; i += 1024) {
    float4 v = *(const float4*)(xp + i);
    s += v.x + v.y + v.z + v.w;
    ss += v.x * v.x + v.y * v.y + v.z * v.z + v.w * v.w;
  }
  __shared__ float r1[256], r2[256];
  r1[t] = s; r2[t] = ss;
  __syncthreads();
  for (int off = 128; off > 0; off >>= 1) {
    if (t < off) { r1[t] += r1[t + off]; r2[t] += r2[t + off]; }
    __syncthreads();
  }
  float mean = r1[0] * (1.f / (CPG * NSP));
  float var  = r2[0] * (1.f / (CPG * NSP)) - mean * mean;
  float rstd = rsqrtf(var + GEPS);
  float wv[CPG], bv[CPG];
  for (int c = 0; c < CPG; c++) {
    wv[c] = w[g * CPG + c] * rstd;
    bv[c] = bias[g * CPG + c] - mean * wv[c];
  }
  for (int n = t; n < NSP; n += 256) {
    s8v pk;
    for (int c = 0; c < CPG; c++) {
      float v = xp[(size_t)c * NSP + n];
      ((unsigned short*)&pk)[c] = f2b(v * wv[c] + bv[c]);
    }
    *(s8v*)(xn + ((size_t)(b * NSP + n) * NC + g * CPG)) = pk;
  }
}

// ------ Generic NT GEMM: C[m][n] = scale*sum_k A[m][k]*Bt[n][k] (+bias[m]) (+res) ------
template<int STORE_T, int HAS_BIAS, int HAS_RES, int F32OUT>
__global__ __launch_bounds__(256) void gemm_nt(
    const unsigned short* __restrict__ A, const unsigned short* __restrict__ Bt,
    void* __restrict__ Cv, const float* __restrict__ bias,
    const float* __restrict__ res,
    int M, int N, int K, int ldC, float scale,
    long long sA, long long sB, long long sC, long long sR) {
  A  += (size_t)blockIdx.z * sA;
  Bt += (size_t)blockIdx.z * sB;
  if (HAS_RES) res += (size_t)blockIdx.z * sR;
  const int m0 = blockIdx.y * 128, n0 = blockIdx.x * 128;
  __shared__ unsigned short As[128 * 32], Bs[128 * 32];
  const int t = threadIdx.x;
  const int lane = t & 63, wave = t >> 6;
  const int wm = (wave >> 1) * 64, wn = (wave & 1) * 64;
  const int l16 = lane & 15, quad = lane >> 4;
  const int srow = t >> 2, skc = (t & 3) * 8;

  f4v acc[4][4];
  for (int mi = 0; mi < 4; mi++)
    for (int ni = 0; ni < 4; ni++)
      acc[mi][ni] = (f4v){0.f, 0.f, 0.f, 0.f};

  const unsigned short* Ag0 = A  + (size_t)(m0 + srow) * K + skc;
  const unsigned short* Ag1 = A  + (size_t)(m0 + srow + 64) * K + skc;
  const unsigned short* Bg0 = Bt + (size_t)(n0 + srow) * K + skc;
  const unsigned short* Bg1 = Bt + (size_t)(n0 + srow + 64) * K + skc;

  for (int k0 = 0; k0 < K; k0 += 32) {
    s8v a0 = *(const s8v*)(Ag0 + k0);
    s8v a1 = *(const s8v*)(Ag1 + k0);
    s8v b0 = *(const s8v*)(Bg0 + k0);
    s8v b1 = *(const s8v*)(Bg1 + k0);
    __syncthreads();
    *(s8v*)(As + srow * 32 + skc) = a0;
    *(s8v*)(As + (srow + 64) * 32 + skc) = a1;
    *(s8v*)(Bs + srow * 32 + skc) = b0;
    *(s8v*)(Bs + (srow + 64) * 32 + skc) = b1;
    __syncthreads();
    s8v af[4], bfr[4];
    for (int mi = 0; mi < 4; mi++)
      af[mi] = *(const s8v*)(As + (wm + mi * 16 + l16) * 32 + quad * 8);
    for (int ni = 0; ni < 4; ni++)
      bfr[ni] = *(const s8v*)(Bs + (wn + ni * 16 + l16) * 32 + quad * 8);
    for (int mi = 0; mi < 4; mi++)
      for (int ni = 0; ni < 4; ni++)
        acc[mi][ni] = __builtin_amdgcn_mfma_f32_16x16x32_bf16(af[mi], bfr[ni], acc[mi][ni], 0, 0, 0);
  }

  for (int mi = 0; mi < 4; mi++) {
    const int rb = m0 + wm + mi * 16 + quad * 4;
    for (int ni = 0; ni < 4; ni++) {
      const int col = n0 + wn + ni * 16 + l16;
      f4v a = acc[mi][ni];
      if (F32OUT) {
        float* C = (float*)Cv + (size_t)blockIdx.z * sC;
        for (int r = 0; r < 4; r++) {
          float v = a[r] * scale;
          if (HAS_BIAS) v += bias[rb + r];
          if (HAS_RES) v += res[(size_t)(rb + r) * ldC + col];
          C[(size_t)(rb + r) * ldC + col] = v;
        }
      } else {
        unsigned short* C = (unsigned short*)Cv + (size_t)blockIdx.z * sC;
        if (STORE_T) {
          us4v pk;
          for (int r = 0; r < 4; r++) {
            float v = a[r] * scale;
            if (HAS_BIAS) v += bias[rb + r];
            pk[r] = (unsigned short)f2b(v);
          }
          *(us4v*)(C + (size_t)col * ldC + rb) = pk;
        } else {
          for (int r = 0; r < 4; r++) {
            float v = a[r] * scale;
            if (HAS_BIAS) v += bias[rb + r];
            if (HAS_RES) v += res[(size_t)(rb + r) * ldC + col];
            C[(size_t)(rb + r) * ldC + col] = f2b(v);
          }
        }
      }
    }
  }
}

// ---- Flash v3: LDS K/V in FRAGMENT ORDER via global_load_lds(16B); j-split x4 ----
// grid (NSP/64, NB, JSPLIT), 256 thr, 4 blocks/CU. Wave w owns Q-rows qt*64+w*16..+16.
__global__ __launch_bounds__(256, 4) void flash3_kernel(
    const unsigned short* __restrict__ q, const unsigned short* __restrict__ k,
    const unsigned short* __restrict__ v, unsigned short* __restrict__ Opart,
    float2* __restrict__ MLpart) {
  const int qt = blockIdx.x, b = blockIdx.y, js = blockIdx.z;
  const size_t sNC = (size_t)NSP * NC;
  const unsigned short* qb = q + b * sNC;
  const unsigned short* kb = k + b * sNC;
  const unsigned short* vb = v + b * sNC;
  const int t = threadIdx.x, lane = t & 63, w = t >> 6;
  const int l16 = lane & 15, quad = lane >> 4;

  // K fragments: 16 slots (s*8+kc), each 64 lanes x 16B. V fragments: 16 slots (dt).
  __shared__ unsigned short KfLds[16 * 512];
  __shared__ unsigned short VfLds[16 * 512];
  __shared__ unsigned short Ps[4][16 * 40];
  unsigned short* Pw = Ps[w];

  const int ibase = qt * 64 + w * 16;
  s8v qf[8];
  for (int kc = 0; kc < 8; kc++)
    qf[kc] = *(const s8v*)(qb + (size_t)(ibase + l16) * NC + kc * 32 + quad * 8);

  f4v accO[16];
  for (int dt = 0; dt < 16; dt++) accO[dt] = (f4v){0.f, 0.f, 0.f, 0.f};
  float m_r[4], l_r[4];
  for (int r = 0; r < 4; r++) { m_r[r] = -1e30f; l_r[r] = 0.f; }

  const int jbeg = js * (NSP / JSPLIT);
  for (int jt = 0; jt < (NSP / JSPLIT) / 32; jt++) {
    const int j0 = jbeg + jt * 32;
    __syncthreads();  // previous tile's compute done before overwrite
    // ---- stage 32 fragment-slots (8 per wave) via global_load_lds width=16 ----
    if (w < 2) {
      for (int ii = 0; ii < 8; ii++) {
        const int idx = w * 8 + ii;            // 0..15: s=idx>>3, kc=idx&7
        const int s = idx >> 3, kc = idx & 7;
        const unsigned short* gp =
            kb + (size_t)(j0 + s * 16 + l16) * NC + kc * 32 + quad * 8;
        __builtin_amdgcn_global_load_lds(
            (const __attribute__((address_space(1))) unsigned int*)gp,
            (__attribute__((address_space(3))) unsigned int*)(KfLds + idx * 512),
            16, 0, 0);
      }
    } else {
      for (int ii = 0; ii < 8; ii++) {
        const int dt = (w - 2) * 8 + ii;       // 0..15
        const unsigned short* gp =
            vb + (size_t)(dt * 16 + l16) * NSP + j0 + quad * 8;
        __builtin_amdgcn_global_load_lds(
            (const __attribute__((address_space(1))) unsigned int*)gp,
            (__attribute__((address_space(3))) unsigned int*)(VfLds + dt * 512),
            16, 0, 0);
      }
    }
    __syncthreads();  // vmcnt(0) drain + barrier

    // ---- QK^T: 2 j-subtiles of 16; frag reads are sequential (conflict-free) ----
    f4v accS[2];
    accS[0] = (f4v){0.f, 0.f, 0.f, 0.f};
    accS[1] = (f4v){0.f, 0.f, 0.f, 0.f};
    for (int kc = 0; kc < 8; kc++) {
      s8v kf0 = *(const s8v*)(KfLds + kc * 512 + lane * 8);
      s8v kf1 = *(const s8v*)(KfLds + (8 + kc) * 512 + lane * 8);
      accS[0] = __builtin_amdgcn_mfma_f32_16x16x32_bf16(qf[kc], kf0, accS[0], 0, 0, 0);
      accS[1] = __builtin_amdgcn_mfma_f32_16x16x32_bf16(qf[kc], kf1, accS[1], 0, 0, 0);
    }

    // ---- online softmax (rows quad*4+r; 16-lane row groups) ----
    float al_r[4], p[2][4];
    for (int r = 0; r < 4; r++) {
      float mv = fmaxf(accS[0][r], accS[1][r]) * SCALE;
      for (int msk = 1; msk < 16; msk <<= 1) mv = fmaxf(mv, __shfl_xor(mv, msk, 64));
      const float mt = fmaxf(m_r[r], mv);
      const float al = __expf(m_r[r] - mt);
      const float p0 = __expf(accS[0][r] * SCALE - mt);
      const float p1 = __expf(accS[1][r] * SCALE - mt);
      p[0][r] = p0; p[1][r] = p1;
      float s_sum = p0 + p1;
      for (int msk = 1; msk < 16; msk <<= 1) s_sum += __shfl_xor(s_sum, msk, 64);
      l_r[r] = l_r[r] * al + s_sum;
      m_r[r] = mt;
      al_r[r] = al;
    }
    for (int dt = 0; dt < 16; dt++)
      for (int r = 0; r < 4; r++) accO[dt][r] *= al_r[r];

    // ---- P: C-layout -> wave-local LDS -> A-frag ----
    for (int n = 0; n < 2; n++)
      for (int r = 0; r < 4; r++)
        Pw[(quad * 4 + r) * 40 + n * 16 + l16] = f2b(p[n][r]);
    s8v pf = *(const s8v*)(Pw + l16 * 40 + quad * 8);

    // ---- PV: V frags sequential from LDS ----
    for (int dt = 0; dt < 16; dt++) {
      s8v vf = *(const s8v*)(VfLds + dt * 512 + lane * 8);
      accO[dt] = __builtin_amdgcn_mfma_f32_16x16x32_bf16(pf, vf, accO[dt], 0, 0, 0);
    }
  }

  // ---- store partials: O unnormalized bf16, (m,l) per row ----
  const int prow = b * NSP + ibase;
  unsigned short* Op = Opart + ((size_t)js * NROWS + prow) * NC;
  for (int dt = 0; dt < 16; dt++)
    for (int r = 0; r < 4; r++)
      Op[(size_t)(quad * 4 + r) * NC + dt * 16 + l16] = f2b(accO[dt][r]);
  if (l16 == 0)
    for (int r = 0; r < 4; r++)
      MLpart[(size_t)js * NROWS + prow + quad * 4 + r] = make_float2(m_r[r], l_r[r]);
}

// ---- merge JSPLIT partials -> at (B,N,C) bf16. grid NROWS/4, wave per row. ----
__global__ __launch_bounds__(256) void merge_kernel(
    const unsigned short* __restrict__ Opart, const float2* __restrict__ MLpart,
    unsigned short* __restrict__ at) {
  const int t = threadIdx.x;
  const int row = blockIdx.x * 4 + (t >> 6);
  const int d0 = (t & 63) * 4;
  float2 ml[JSPLIT];
  float m = -1e30f;
  for (int js = 0; js < JSPLIT; js++) {
    ml[js] = MLpart[(size_t)js * NROWS + row];
    m = fmaxf(m, ml[js].x);
  }
  float e[JSPLIT], lsum = 0.f;
  for (int js = 0; js < JSPLIT; js++) {
    e[js] = __expf(ml[js].x - m);
    lsum += ml[js].y * e[js];
  }
  const float inv = 1.f / lsum;
  float acc[4] = {0.f, 0.f, 0.f, 0.f};
  for (int js = 0; js < JSPLIT; js++) {
    us4v o = *(const us4v*)(Opart + ((size_t)js * NROWS + row) * NC + d0);
    for (int i = 0; i < 4; i++) acc[i] += e[js] * b2f(o[i]);
  }
  us4v pk;
  for (int i = 0; i < 4; i++) pk[i] = f2b(acc[i] * inv);
  *(us4v*)(at + (size_t)row * NC + d0) = pk;
}

extern "C" void kernel_launch(void* const* d_in, const int* in_sizes, int n_in,
                              void* d_out, int out_size, void* d_ws, size_t ws_size,
                              hipStream_t stream) {
  const float* x      = (const float*)d_in[0];
  const float* norm_w = (const float*)d_in[1];
  const float* norm_b = (const float*)d_in[2];
  const float* qkv_w  = (const float*)d_in[3];
  const float* qkv_b  = (const float*)d_in[4];
  const float* proj_w = (const float*)d_in[5];
  const float* proj_b = (const float*)d_in[6];
  float* out = (float*)d_out;  // fp32 output

  char* ws = (char*)d_ws;
  unsigned short* wq = (unsigned short*)ws;                     // 384 KB
  unsigned short* wp = (unsigned short*)(ws + 3 * NC * NC * 2); // 128 KB
  char* wst = ws + (1 << 20);
  const size_t szBNC = (size_t)NB * NSP * NC * 2;  // 8.4 MB (bf16)
  unsigned short* xn = (unsigned short*)wst;              // reused as `at`
  unsigned short* q  = (unsigned short*)(wst + szBNC);
  unsigned short* k  = (unsigned short*)(wst + 2 * szBNC);
  unsigned short* v  = (unsigned short*)(wst + 3 * szBNC);
  unsigned short* at = xn;
  unsigned short* Opart = (unsigned short*)(wst + 4 * szBNC);  // 4*16384*256 bf16 = 33.6 MB
  float2* MLpart = (float2*)(wst + 4 * szBNC + (size_t)JSPLIT * NROWS * NC * 2);  // 512 KB
  // peak ws: 1 + 33.6 + 33.6 + 0.5 = 68.7 MB (proven-safe <= 76.6 MB)

  cvt_kernel<<<dim3(3 * NC * NC / 1024), 256, 0, stream>>>(qkv_w, wq, 3 * NC * NC);
  cvt_kernel<<<dim3(NC * NC / 1024), 256, 0, stream>>>(proj_w, wp, NC * NC);
  gn_kernel<<<dim3(NB * NG), 256, 0, stream>>>(x, norm_w, norm_b, xn);

  const long long sNC = (long long)NSP * NC;
  gemm_nt<1, 1, 0, 0><<<dim3(NSP / 128, NC / 128, NB), 256, 0, stream>>>(
      wq, xn, q, qkv_b, nullptr, NC, NSP, NC, NC, 1.f, 0, sNC, sNC, 0);
  gemm_nt<1, 1, 0, 0><<<dim3(NSP / 128, NC / 128, NB), 256, 0, stream>>>(
      wq + NC * NC, xn, k, qkv_b + NC, nullptr, NC, NSP, NC, NC, 1.f, 0, sNC, sNC, 0);
  gemm_nt<0, 1, 0, 0><<<dim3(NSP / 128, NC / 128, NB), 256, 0, stream>>>(
      wq + 2 * NC * NC, xn, v, qkv_b + 2 * NC, nullptr, NC, NSP, NC, NSP, 1.f, 0, sNC, sNC, 0);

  flash3_kernel<<<dim3(NSP / 64, NB, JSPLIT), 256, 0, stream>>>(q, k, v, Opart, MLpart);
  merge_kernel<<<dim3(NROWS / 4), 256, 0, stream>>>(Opart, MLpart, at);

  gemm_nt<0, 1, 1, 1><<<dim3(NSP / 128, NC / 128, NB), 256, 0, stream>>>(
      wp, at, out, proj_b, x, NC, NSP, NC, NSP, 1.f, 0, sNC, sNC, sNC);
}